// Round 7
// baseline (490.247 us; speedup 1.0000x reference)
//
#include <hip/hip_runtime.h>
#include <stdint.h>

// ---------------------------------------------------------------------------
// GraphSAGE(min) x3 + BatchNorm + ReLU + log_softmax, fp32, MI355X (gfx950)
//
// R5: dst-major CSR + dst-range-partitioned fill; BN fused into consumers.
// R6: fully fused per-layer kernel. One wave per node: gather-min (8-wide
//     ILP) -> stage 2x64-float rows in LDS (wave-local, lgkmcnt fence, no
//     __syncthreads) -> GEMM with weight columns in 128 VGPRs (static
//     unrolled) + 4 split accumulators. Kills agg round-trip (25.6MB/layer)
//     and the 2-blocks/CU lockstep k_gemm64 (54us x2). hist fused into
//     convert. Stats: float thread-partials -> double finalize.
// ---------------------------------------------------------------------------

#define NG 8  // dst-range groups for fill (== XCDs)

__device__ __forceinline__ float bnrelu1(float v, float mu, float is, float g, float b) {
    return fmaxf((v - mu) * is * g + b, 0.0f);
}

// ---------------------------------------------------------------------------
// zero deg + detect edge dtype (int64 => odd int32 slots all zero)
__global__ __launch_bounds__(256)
void k_prep(int* __restrict__ deg, int n_nodes, const int* __restrict__ ei32,
            int* __restrict__ flag) {
    int i = blockIdx.x * blockDim.x + threadIdx.x;
    int stride = gridDim.x * blockDim.x;
    for (int j = i; j < n_nodes; j += stride) deg[j] = 0;
    if (i == 0) {
        int allzero = 1;
        for (int t = 1; t < 32; t += 2) allzero &= (ei32[t] == 0);
        *flag = allzero;
    }
}

// ---------------------------------------------------------------------------
// edge_index -> int32 src/dst + degree histogram in one pass
__global__ __launch_bounds__(256)
void k_convert_hist(const void* __restrict__ ei, int n_edges,
                    const int* __restrict__ flag, int* __restrict__ src32,
                    int* __restrict__ dst32, int* __restrict__ deg) {
    const bool is64 = (*flag != 0);
    const int* e32 = (const int*)ei;
    const long long* e64 = (const long long*)ei;
    int i = blockIdx.x * blockDim.x + threadIdx.x;
    int stride = gridDim.x * blockDim.x;
    for (int e = i; e < n_edges; e += stride) {
        int s, d;
        if (is64) { s = (int)e64[e]; d = (int)e64[n_edges + e]; }
        else      { s = e32[e];      d = e32[n_edges + e]; }
        src32[e] = s;
        dst32[e] = d;
        atomicAdd(&deg[d], 1);
    }
}

// ---------------------------------------------------------------------------
// hierarchical scan
__global__ __launch_bounds__(256)
void k_scan1(const int* __restrict__ deg, int* __restrict__ bsum, int n) {
    __shared__ int red[256];
    const int t = threadIdx.x;
    const int i = blockIdx.x * 256 + t;
    red[t] = (i < n) ? deg[i] : 0;
    __syncthreads();
    for (int off = 128; off; off >>= 1) {
        if (t < off) red[t] += red[t + off];
        __syncthreads();
    }
    if (t == 0) bsum[blockIdx.x] = red[0];
}

__global__ __launch_bounds__(1024)
void k_scan2(const int* __restrict__ bsum, int* __restrict__ boffs,
             int nb, int* __restrict__ rowptr, int n) {
    __shared__ int part[1024];
    const int t = threadIdx.x;
    part[t] = (t < nb) ? bsum[t] : 0;
    __syncthreads();
    for (int off = 1; off < 1024; off <<= 1) {
        int v = (t >= off) ? part[t - off] : 0;
        __syncthreads();
        part[t] += v;
        __syncthreads();
    }
    if (t < nb) boffs[t] = (t == 0) ? 0 : part[t - 1];
    if (t == 0) rowptr[n] = part[nb - 1];
}

__global__ __launch_bounds__(256)
void k_scan3(const int* __restrict__ deg, const int* __restrict__ boffs,
             int* __restrict__ rowptr, int* __restrict__ cursor, int n) {
    __shared__ int part[256];
    const int t = threadIdx.x;
    const int i = blockIdx.x * 256 + t;
    const int d = (i < n) ? deg[i] : 0;
    part[t] = d;
    __syncthreads();
    for (int off = 1; off < 256; off <<= 1) {
        int v = (t >= off) ? part[t - off] : 0;
        __syncthreads();
        part[t] += v;
        __syncthreads();
    }
    if (i < n) {
        int excl = boffs[blockIdx.x] + part[t] - d;
        rowptr[i] = excl;
        cursor[i] = excl;
    }
}

// ---------------------------------------------------------------------------
// dst-range-partitioned fill: group g's csr writes land in one contiguous
// XCD-local region; CSR layout stays dst-major for the consumer.
__global__ __launch_bounds__(256)
void k_fill_r(const int* __restrict__ src32, const int* __restrict__ dst32,
              int n_edges, int* __restrict__ cursor, int* __restrict__ csr,
              int NN, int blocks_per_group) {
    const int g = blockIdx.x & (NG - 1);
    const int jb = blockIdx.x >> 3;
    const int lo = (int)((long long)g * NN / NG);
    const int hi = (int)((long long)(g + 1) * NN / NG);
    const int stride = blocks_per_group * 256;
    for (int e = jb * 256 + threadIdx.x; e < n_edges; e += stride) {
        int d = dst32[e];
        if (d >= lo && d < hi) {
            int pos = atomicAdd(&cursor[d], 1);
            csr[pos] = src32[e];
        }
    }
}

// ---------------------------------------------------------------------------
// fused layer: wave per node. gather-min (BN'd per element if BN) -> rows in
// LDS (wave-local) -> 64->64 GEMM with weight columns in VGPRs -> stats.
template <bool BN>
__global__ __launch_bounds__(256, 2)
void k_layer(const float* __restrict__ xin, const int* __restrict__ rowptr,
             const int* __restrict__ csr, const float* __restrict__ Wl,
             const float* __restrict__ bl, const float* __restrict__ Wr,
             float* __restrict__ hout, float* __restrict__ psum,
             float* __restrict__ psq, int NN,
             const float* __restrict__ mu, const float* __restrict__ istd,
             const float* __restrict__ gam, const float* __restrict__ bet) {
    __shared__ float rowA[4][64];
    __shared__ float rowX[4][64];
    __shared__ float red[4][64];
    const int t = threadIdx.x, lane = t & 63, w = t >> 6;
    // weight columns in VGPRs (static unrolled indices -> no scratch)
    float wl[64], wr[64];
#pragma unroll
    for (int k = 0; k < 64; ++k) {
        wl[k] = Wl[k * 64 + lane];
        wr[k] = Wr[k * 64 + lane];
    }
    float s_mu = 0.f, s_is = 0.f, s_g = 0.f, s_b = 0.f;
    if (BN) { s_mu = mu[lane]; s_is = istd[lane]; s_g = gam[lane]; s_b = bet[lane]; }
    const float bc = bl[lane];
    float lsum = 0.f, lsq = 0.f;
    const int wave = blockIdx.x * 4 + w;
    const int nwaves = gridDim.x * 4;
    for (int n = wave; n < NN; n += nwaves) {
        const int beg = rowptr[n], end = rowptr[n + 1];
        float m = __builtin_inff();
        int e = beg;
        for (; e + 8 <= end; e += 8) {  // 8 gathers in flight
            int s0 = csr[e], s1 = csr[e + 1], s2 = csr[e + 2], s3 = csr[e + 3];
            int s4 = csr[e + 4], s5 = csr[e + 5], s6 = csr[e + 6], s7 = csr[e + 7];
            float v0 = xin[(size_t)s0 * 64 + lane];
            float v1 = xin[(size_t)s1 * 64 + lane];
            float v2 = xin[(size_t)s2 * 64 + lane];
            float v3 = xin[(size_t)s3 * 64 + lane];
            float v4 = xin[(size_t)s4 * 64 + lane];
            float v5 = xin[(size_t)s5 * 64 + lane];
            float v6 = xin[(size_t)s6 * 64 + lane];
            float v7 = xin[(size_t)s7 * 64 + lane];
            if (BN) {
                v0 = bnrelu1(v0, s_mu, s_is, s_g, s_b);
                v1 = bnrelu1(v1, s_mu, s_is, s_g, s_b);
                v2 = bnrelu1(v2, s_mu, s_is, s_g, s_b);
                v3 = bnrelu1(v3, s_mu, s_is, s_g, s_b);
                v4 = bnrelu1(v4, s_mu, s_is, s_g, s_b);
                v5 = bnrelu1(v5, s_mu, s_is, s_g, s_b);
                v6 = bnrelu1(v6, s_mu, s_is, s_g, s_b);
                v7 = bnrelu1(v7, s_mu, s_is, s_g, s_b);
            }
            m = fminf(m, fminf(fminf(fminf(v0, v1), fminf(v2, v3)),
                               fminf(fminf(v4, v5), fminf(v6, v7))));
        }
        for (; e < end; ++e) {
            float v = xin[(size_t)csr[e] * 64 + lane];
            if (BN) v = bnrelu1(v, s_mu, s_is, s_g, s_b);
            m = fminf(m, v);
        }
        const float av = (end > beg) ? m : 0.0f;
        float xv = xin[(size_t)n * 64 + lane];
        if (BN) xv = bnrelu1(xv, s_mu, s_is, s_g, s_b);
        rowA[w][lane] = av;
        rowX[w][lane] = xv;
        // wave-local LDS exchange: same-wave DS ops execute in order; fence
        // completion + pin the schedule (no cross-wave barrier needed).
        asm volatile("s_waitcnt lgkmcnt(0)" ::: "memory");
        __builtin_amdgcn_sched_barrier(0);
        float a0 = 0.f, a1 = 0.f, a2 = 0.f, a3 = 0.f;  // split acc chains
#pragma unroll
        for (int k4 = 0; k4 < 16; ++k4) {
            const float4 a4 = *(const float4*)&rowA[w][k4 * 4];  // broadcast b128
            const float4 x4 = *(const float4*)&rowX[w][k4 * 4];
            a0 = fmaf(a4.x, wl[k4 * 4 + 0], a0);
            a1 = fmaf(a4.y, wl[k4 * 4 + 1], a1);
            a2 = fmaf(a4.z, wl[k4 * 4 + 2], a2);
            a3 = fmaf(a4.w, wl[k4 * 4 + 3], a3);
            a0 = fmaf(x4.x, wr[k4 * 4 + 0], a0);
            a1 = fmaf(x4.y, wr[k4 * 4 + 1], a1);
            a2 = fmaf(x4.z, wr[k4 * 4 + 2], a2);
            a3 = fmaf(x4.w, wr[k4 * 4 + 3], a3);
        }
        const float h = bc + ((a0 + a1) + (a2 + a3));
        hout[(size_t)n * 64 + lane] = h;
        lsum += h;
        lsq = fmaf(h, h, lsq);
    }
    // per-block stats slot (written unconditionally every call)
    __syncthreads();
    red[w][lane] = lsum;
    __syncthreads();
    if (w == 0)
        psum[(size_t)blockIdx.x * 64 + lane] =
            red[0][lane] + red[1][lane] + red[2][lane] + red[3][lane];
    __syncthreads();
    red[w][lane] = lsq;
    __syncthreads();
    if (w == 0)
        psq[(size_t)blockIdx.x * 64 + lane] =
            red[0][lane] + red[1][lane] + red[2][lane] + red[3][lane];
}

// ---------------------------------------------------------------------------
// float-slot finalize: 1024 thr = 16 groups x 64 ch; double accumulation.
__global__ __launch_bounds__(1024)
void k_finalize(const float* __restrict__ psum, const float* __restrict__ psq,
                float* __restrict__ mu, float* __restrict__ istd,
                int n_nodes, int nblocks) {
    __shared__ double s_s[16][64];
    __shared__ double s_q[16][64];
    const int t = threadIdx.x;
    const int c = t & 63, g = t >> 6;
    double s = 0.0, q = 0.0;
    for (int b = g; b < nblocks; b += 16) {
        s += (double)psum[(size_t)b * 64 + c];
        q += (double)psq[(size_t)b * 64 + c];
    }
    s_s[g][c] = s;
    s_q[g][c] = q;
    __syncthreads();
    if (g == 0) {
        double S = 0.0, Q = 0.0;
#pragma unroll
        for (int i = 0; i < 16; ++i) { S += s_s[i][c]; Q += s_q[i][c]; }
        double m = S / n_nodes;
        double var = Q / n_nodes - m * m;
        mu[c] = (float)m;
        istd[c] = (float)(1.0 / sqrt(var + 1e-5));
    }
}

// ---------------------------------------------------------------------------
// fused layer 3: gather-min(BN) -> 64->16 GEMM (weights in VGPR, lane =
// (k-quarter q, out-channel c)) -> cross-quarter shfl reduce -> log_softmax.
__global__ __launch_bounds__(256, 2)
void k_layer3(const float* __restrict__ xin, const int* __restrict__ rowptr,
              const int* __restrict__ csr, const float* __restrict__ W3l,
              const float* __restrict__ b3, const float* __restrict__ W3r,
              float* __restrict__ out, int NN,
              const float* __restrict__ mu, const float* __restrict__ istd,
              const float* __restrict__ gam, const float* __restrict__ bet) {
    __shared__ float rowA[4][64];
    __shared__ float rowX[4][64];
    const int t = threadIdx.x, lane = t & 63, w = t >> 6;
    const int c = lane & 15, q = lane >> 4;
    float wl3[16], wr3[16];
#pragma unroll
    for (int j = 0; j < 16; ++j) {
        wl3[j] = W3l[(q * 16 + j) * 16 + c];
        wr3[j] = W3r[(q * 16 + j) * 16 + c];
    }
    const float s_mu = mu[lane], s_is = istd[lane], s_g = gam[lane], s_b = bet[lane];
    const float bc = b3[c];
    const int wave = blockIdx.x * 4 + w;
    const int nwaves = gridDim.x * 4;
    for (int n = wave; n < NN; n += nwaves) {
        const int beg = rowptr[n], end = rowptr[n + 1];
        float m = __builtin_inff();
        int e = beg;
        for (; e + 8 <= end; e += 8) {
            int s0 = csr[e], s1 = csr[e + 1], s2 = csr[e + 2], s3 = csr[e + 3];
            int s4 = csr[e + 4], s5 = csr[e + 5], s6 = csr[e + 6], s7 = csr[e + 7];
            float v0 = bnrelu1(xin[(size_t)s0 * 64 + lane], s_mu, s_is, s_g, s_b);
            float v1 = bnrelu1(xin[(size_t)s1 * 64 + lane], s_mu, s_is, s_g, s_b);
            float v2 = bnrelu1(xin[(size_t)s2 * 64 + lane], s_mu, s_is, s_g, s_b);
            float v3 = bnrelu1(xin[(size_t)s3 * 64 + lane], s_mu, s_is, s_g, s_b);
            float v4 = bnrelu1(xin[(size_t)s4 * 64 + lane], s_mu, s_is, s_g, s_b);
            float v5 = bnrelu1(xin[(size_t)s5 * 64 + lane], s_mu, s_is, s_g, s_b);
            float v6 = bnrelu1(xin[(size_t)s6 * 64 + lane], s_mu, s_is, s_g, s_b);
            float v7 = bnrelu1(xin[(size_t)s7 * 64 + lane], s_mu, s_is, s_g, s_b);
            m = fminf(m, fminf(fminf(fminf(v0, v1), fminf(v2, v3)),
                               fminf(fminf(v4, v5), fminf(v6, v7))));
        }
        for (; e < end; ++e)
            m = fminf(m, bnrelu1(xin[(size_t)csr[e] * 64 + lane], s_mu, s_is, s_g, s_b));
        rowA[w][lane] = (end > beg) ? m : 0.0f;
        rowX[w][lane] = bnrelu1(xin[(size_t)n * 64 + lane], s_mu, s_is, s_g, s_b);
        asm volatile("s_waitcnt lgkmcnt(0)" ::: "memory");
        __builtin_amdgcn_sched_barrier(0);
        float p0 = 0.f, p1 = 0.f;
#pragma unroll
        for (int j4 = 0; j4 < 4; ++j4) {
            const float4 a4 = *(const float4*)&rowA[w][q * 16 + j4 * 4];
            const float4 x4 = *(const float4*)&rowX[w][q * 16 + j4 * 4];
            p0 = fmaf(a4.x, wl3[j4 * 4 + 0], p0);
            p1 = fmaf(a4.y, wl3[j4 * 4 + 1], p1);
            p0 = fmaf(a4.z, wl3[j4 * 4 + 2], p0);
            p1 = fmaf(a4.w, wl3[j4 * 4 + 3], p1);
            p0 = fmaf(x4.x, wr3[j4 * 4 + 0], p0);
            p1 = fmaf(x4.y, wr3[j4 * 4 + 1], p1);
            p0 = fmaf(x4.z, wr3[j4 * 4 + 2], p0);
            p1 = fmaf(x4.w, wr3[j4 * 4 + 3], p1);
        }
        float acc = p0 + p1;
        acc += __shfl_xor(acc, 16);   // reduce across 4 k-quarters
        acc += __shfl_xor(acc, 32);
        acc += bc;
        float mx = acc;
        for (int off = 8; off; off >>= 1) mx = fmaxf(mx, __shfl_xor(mx, off, 16));
        float ex = expf(acc - mx);
        float ss = ex;
        for (int off = 8; off; off >>= 1) ss += __shfl_xor(ss, off, 16);
        if (lane < 16) out[(size_t)n * 16 + c] = (acc - mx) - logf(ss);
    }
}

// ---------------------------------------------------------------------------
extern "C" void kernel_launch(void* const* d_in, const int* in_sizes, int n_in,
                              void* d_out, int out_size, void* d_ws, size_t ws_size,
                              hipStream_t stream) {
    (void)n_in; (void)out_size; (void)ws_size;
    const float* x   = (const float*)d_in[0];
    const void*  ei  = d_in[1];
    const float* W1l = (const float*)d_in[2];
    const float* b1  = (const float*)d_in[3];
    const float* W1r = (const float*)d_in[4];
    const float* g1  = (const float*)d_in[5];
    const float* be1 = (const float*)d_in[6];
    const float* W2l = (const float*)d_in[7];
    const float* b2  = (const float*)d_in[8];
    const float* W2r = (const float*)d_in[9];
    const float* g2  = (const float*)d_in[10];
    const float* be2 = (const float*)d_in[11];
    const float* W3l = (const float*)d_in[12];
    const float* b3  = (const float*)d_in[13];
    const float* W3r = (const float*)d_in[14];
    float* out = (float*)d_out;

    const int NN = in_sizes[0] / 64;
    const int n_edges = in_sizes[1] / 2;
    const int nAgg = NN * 64;

    size_t off = 0;
    auto alloc = [&](size_t bytes) {
        void* p = (char*)d_ws + off;
        off = (off + bytes + 255) & ~(size_t)255;
        return p;
    };
    float* hA     = (float*)alloc((size_t)nAgg * 4);
    float* hB     = (float*)alloc((size_t)nAgg * 4);
    int*   csr    = (int*)  alloc((size_t)n_edges * 4);
    int*   src32  = (int*)  alloc((size_t)n_edges * 4);
    int*   dst32  = (int*)  alloc((size_t)n_edges * 4);
    int*   rowptr = (int*)  alloc((size_t)(NN + 1) * 4);
    int*   cursor = (int*)  alloc((size_t)NN * 4);
    int*   deg    = (int*)  alloc((size_t)NN * 4);
    int*   bsum   = (int*)  alloc(1024 * 4);
    int*   boffs  = (int*)  alloc(1024 * 4);
    const int GL = 768;  // 3 blocks/CU target for fused layers
    float* psum   = (float*)alloc((size_t)GL * 64 * 4);
    float* psq    = (float*)alloc((size_t)GL * 64 * 4);
    float* mu1    = (float*)alloc(64 * 4);
    float* istd1  = (float*)alloc(64 * 4);
    float* mu2    = (float*)alloc(64 * 4);
    float* istd2  = (float*)alloc(64 * 4);
    int*   flag   = (int*)  alloc(4);

    const int GHF = 1024;             // fill: 8 groups x 128 blocks
    const int BPG = GHF / NG;
    const int NB = (NN + 255) / 256;  // 196 <= 1024

    // ---- build CSR once ----
    k_prep        <<<256, 256, 0, stream>>>(deg, NN, (const int*)ei, flag);
    k_convert_hist<<<1024, 256, 0, stream>>>(ei, n_edges, flag, src32, dst32, deg);
    k_scan1       <<<NB, 256, 0, stream>>>(deg, bsum, NN);
    k_scan2       <<<1, 1024, 0, stream>>>(bsum, boffs, NB, rowptr, NN);
    k_scan3       <<<NB, 256, 0, stream>>>(deg, boffs, rowptr, cursor, NN);
    k_fill_r      <<<GHF, 256, 0, stream>>>(src32, dst32, n_edges, cursor, csr, NN, BPG);

    // ---- layer 1 (raw x) ----
    k_layer<false><<<GL, 256, 0, stream>>>(x, rowptr, csr, W1l, b1, W1r, hA,
                                           psum, psq, NN,
                                           nullptr, nullptr, nullptr, nullptr);
    k_finalize<<<1, 1024, 0, stream>>>(psum, psq, mu1, istd1, NN, GL);
    // ---- layer 2 (BN1 fused) ----
    k_layer<true><<<GL, 256, 0, stream>>>(hA, rowptr, csr, W2l, b2, W2r, hB,
                                          psum, psq, NN, mu1, istd1, g1, be1);
    k_finalize<<<1, 1024, 0, stream>>>(psum, psq, mu2, istd2, NN, GL);
    // ---- layer 3 (BN2 fused) + log_softmax ----
    k_layer3<<<GL, 256, 0, stream>>>(hB, rowptr, csr, W3l, b3, W3r, out, NN,
                                     mu2, istd2, g2, be2);
}